// Round 1
// baseline (496.504 us; speedup 1.0000x reference)
//
#include <hip/hip_runtime.h>

#define B_    8
#define CIN_  64
#define COUT_ 64
#define H_    256
#define W_    256

// ---------------------------------------------------------------------------
// Kernel 1: materialize per-batch aggregated weights
// agg[b][co][ci][kh*3+kw] = weight + tb*mb*att[b,1] + tq*mq*att[b,2]
//                                  + (tn*mn + tx*mx)*att[b,0]
// ---------------------------------------------------------------------------
__global__ __launch_bounds__(256) void prep_weights_kernel(
    const float* __restrict__ att,     // [B][10]
    const float* __restrict__ weight,  // [COUT][CIN][9]
    const float* __restrict__ tb, const float* __restrict__ tq,
    const float* __restrict__ tn, const float* __restrict__ tx,
    const float* __restrict__ mb, const float* __restrict__ mq,
    const float* __restrict__ mn, const float* __restrict__ mx,
    float* __restrict__ agg)           // [B][COUT][CIN][9]
{
    int idx = blockIdx.x * 256 + threadIdx.x;
    const int per_b = COUT_ * CIN_ * 9;
    if (idx >= B_ * per_b) return;
    int b = idx / per_b;
    int r = idx - b * per_b;       // co*CIN*9 + ci*9 + k
    int cc = r / 9;                // co*CIN + ci  (mask index, masks are [COUT][CIN][1][1])
    float a0 = att[b * 10 + 0];
    float a1 = att[b * 10 + 1];
    float a2 = att[b * 10 + 2];
    float dyn = tb[r] * mb[cc] * a1
              + tq[r] * mq[cc] * a2
              + (tn[r] * mn[cc] + tx[r] * mx[cc]) * a0;
    agg[idx] = weight[r] + dyn;
}

// ---------------------------------------------------------------------------
// Kernel 2: direct 3x3 conv, per-batch weights.
// Block: 256 threads. Tile: 8 cout x 32x32 output pixels, one batch.
// Each thread: col = t&31, rows row0..row0+3 (row0 = (t>>5)*4), all 8 couts.
// Per ci: stage 34x34 x-tile in LDS; 18 ds_read feed 288 FMAs.
// ---------------------------------------------------------------------------
__global__ __launch_bounds__(256) void conv_kernel(
    const float* __restrict__ x,     // [B][CIN][H][W]
    const float* __restrict__ agg,   // [B][COUT][CIN][9]
    const float* __restrict__ bias,  // [COUT]
    float* __restrict__ out)         // [B][COUT][H][W]
{
    __shared__ float xs[34 * 34];

    const int s   = blockIdx.x;      // 0..63 spatial tile
    const int cog = blockIdx.y;      // 0..7 cout group (8 couts each)
    const int b   = blockIdx.z;      // 0..7 batch

    const int tx_ = s & 7;
    const int ty_ = s >> 3;
    const int x0  = tx_ * 32;
    const int y0  = ty_ * 32;

    const int t    = threadIdx.x;
    const int col  = t & 31;
    const int row0 = (t >> 5) * 4;   // 0,4,...,28

    // Precompute staging-load offsets (fixed across ci).
    int  off_[5];
    bool val_[5];
#pragma unroll
    for (int i = 0; i < 5; ++i) {
        int l = t + 256 * i;
        int r = l / 34;
        int c = l - r * 34;
        int gy = y0 + r - 1;
        int gx = x0 + c - 1;
        bool v = (l < 34 * 34) && gy >= 0 && gy < H_ && gx >= 0 && gx < W_;
        off_[i] = v ? (gy * W_ + gx) : 0;
        val_[i] = v;
    }

    float acc[8][4];
#pragma unroll
    for (int c = 0; c < 8; ++c)
#pragma unroll
        for (int p = 0; p < 4; ++p) acc[c][p] = 0.f;

    const size_t xplane = (size_t)H_ * W_;
    const float* xbase = x + (size_t)b * CIN_ * xplane;
    // agg slice for (b, cog*8 .. cog*8+7, ci, :): co stride = CIN_*9
    const float* wbase = agg + ((size_t)(b * COUT_ + cog * 8) * CIN_) * 9;

    for (int ci = 0; ci < CIN_; ++ci) {
        const float* xp = xbase + (size_t)ci * xplane;
#pragma unroll
        for (int i = 0; i < 5; ++i) {
            int l = t + 256 * i;
            if (l < 34 * 34) {
                float v = val_[i] ? xp[off_[i]] : 0.f;
                xs[l] = v;
            }
        }
        __syncthreads();

        // 18 LDS reads: rows row0..row0+5, cols col..col+2
        float xr[6][3];
#pragma unroll
        for (int rr = 0; rr < 6; ++rr)
#pragma unroll
            for (int kc = 0; kc < 3; ++kc)
                xr[rr][kc] = xs[(row0 + rr) * 34 + col + kc];

        const float* wp = wbase + (size_t)ci * 9;
#pragma unroll
        for (int c = 0; c < 8; ++c) {
            float w[9];
#pragma unroll
            for (int k = 0; k < 9; ++k)
                w[k] = wp[(size_t)c * (CIN_ * 9) + k];   // wave-uniform -> s_load
#pragma unroll
            for (int p = 0; p < 4; ++p) {
                float sacc = acc[c][p];
#pragma unroll
                for (int kh = 0; kh < 3; ++kh)
#pragma unroll
                    for (int kw = 0; kw < 3; ++kw)
                        sacc = fmaf(xr[p + kh][kw], w[kh * 3 + kw], sacc);
                acc[c][p] = sacc;
            }
        }
        __syncthreads();
    }

    // Epilogue: add bias, store.
#pragma unroll
    for (int c = 0; c < 8; ++c) {
        int co = cog * 8 + c;
        float bs = bias[co];
#pragma unroll
        for (int p = 0; p < 4; ++p) {
            int oy = y0 + row0 + p;
            int ox = x0 + col;
            out[((size_t)(b * COUT_ + co) * H_ + oy) * W_ + ox] = acc[c][p] + bs;
        }
    }
}

extern "C" void kernel_launch(void* const* d_in, const int* in_sizes, int n_in,
                              void* d_out, int out_size, void* d_ws, size_t ws_size,
                              hipStream_t stream) {
    const float* x      = (const float*)d_in[0];
    const float* att    = (const float*)d_in[1];
    const float* weight = (const float*)d_in[2];
    const float* tb     = (const float*)d_in[3];
    const float* tq     = (const float*)d_in[4];
    const float* tn     = (const float*)d_in[5];
    const float* tx     = (const float*)d_in[6];
    const float* mb     = (const float*)d_in[7];
    const float* mq     = (const float*)d_in[8];
    const float* mn     = (const float*)d_in[9];
    const float* mx     = (const float*)d_in[10];
    const float* bias   = (const float*)d_in[11];
    float* agg = (float*)d_ws;          // B*COUT*CIN*9 floats = 1.18 MB
    float* outp = (float*)d_out;

    int n_agg = B_ * COUT_ * CIN_ * 9;
    prep_weights_kernel<<<(n_agg + 255) / 256, 256, 0, stream>>>(
        att, weight, tb, tq, tn, tx, mb, mq, mn, mx, agg);

    dim3 grid(64, 8, 8);   // spatial tiles, cout groups, batch
    conv_kernel<<<grid, 256, 0, stream>>>(x, agg, bias, outp);
}

// Round 2
// 193.367 us; speedup vs baseline: 2.5677x; 2.5677x over previous
//
#include <hip/hip_runtime.h>

#define B_    8
#define CIN_  64
#define COUT_ 64
#define H_    256
#define W_    256
#define HW_   65536

typedef __attribute__((ext_vector_type(8))) short short8;   // 8 bf16 = 4 VGPRs
typedef __attribute__((ext_vector_type(4))) float f32x4;

static __device__ __forceinline__ unsigned short f2bf(float f) {
    union { float f; unsigned u; } v; v.f = f;
    unsigned r = (v.u + 0x7FFFu + ((v.u >> 16) & 1u)) >> 16;  // RNE
    return (unsigned short)r;
}

// ---------------------------------------------------------------------------
// Kernel 1: aggregate weights -> bf16, layout aggb[b][tap][co][ci]
// ---------------------------------------------------------------------------
__global__ __launch_bounds__(256) void prep_weights_kernel(
    const float* __restrict__ att,     // [B][10]
    const float* __restrict__ weight,  // [COUT][CIN][9]
    const float* __restrict__ tb, const float* __restrict__ tq,
    const float* __restrict__ tn, const float* __restrict__ tx,
    const float* __restrict__ mb, const float* __restrict__ mq,
    const float* __restrict__ mn, const float* __restrict__ mx,
    unsigned short* __restrict__ aggb) // [B][9][COUT][CIN] bf16
{
    int idx = blockIdx.x * 256 + threadIdx.x;
    if (idx >= B_ * 9 * COUT_ * CIN_) return;
    int b    = idx / (9 * COUT_ * CIN_);
    int rem  = idx - b * (9 * COUT_ * CIN_);
    int tap  = rem / (COUT_ * CIN_);
    int rem2 = rem & (COUT_ * CIN_ - 1);
    int co   = rem2 >> 6;
    int ci   = rem2 & 63;

    int r  = (co * CIN_ + ci) * 9 + tap;   // [co][ci][kh][kw]
    int cc = co * CIN_ + ci;

    float a0 = att[b * 10 + 0];
    float a1 = att[b * 10 + 1];
    float a2 = att[b * 10 + 2];
    float val = weight[r]
              + tb[r] * mb[cc] * a1
              + tq[r] * mq[cc] * a2
              + (tn[r] * mn[cc] + tx[r] * mx[cc]) * a0;
    aggb[idx] = f2bf(val);
}

// ---------------------------------------------------------------------------
// Kernel 2: implicit-GEMM conv via mfma_f32_16x16x32_bf16.
// Block: 256 thr = 4 waves. Tile: 64 cout x (4 rows x 64 cols), one batch.
// LDS x-tile: [s = yy*66+xx][ci 0..63] bf16, 16B-slot XOR swizzle (slot ^= s&7).
// Wave wv: cols wv*16..wv*16+15, all 4 rows, all 64 couts.
// K-loop: 9 taps x 2 ci-halves; A-frags from global (L1/L2-hot weights).
// ---------------------------------------------------------------------------
__global__ __launch_bounds__(256, 3) void conv_kernel(
    const float* __restrict__ x,            // [B][CIN][H][W] fp32
    const unsigned short* __restrict__ aggb,// [B][9][COUT][CIN] bf16
    const float* __restrict__ bias,         // [COUT]
    float* __restrict__ out)                // [B][COUT][H][W] fp32
{
    __shared__ unsigned short xs[6 * 66 * 64];   // 50688 B
    unsigned* xsw = (unsigned*)xs;

    const int t  = threadIdx.x;
    const int bz = blockIdx.z;
    const int y0 = blockIdx.y * 4;
    const int x0 = blockIdx.x * 64;

    const float* xp = x + (size_t)bz * CIN_ * HW_;

    // ---- stage x tile (6 rows x 66 cols x 64 ci) as bf16, swizzled ----
    // jobs: p = ci-pair (0..31), s = yy*66+xx (0..395); 12672 jobs total
    for (int it = 0; it < 50; ++it) {
        int idx = it * 256 + t;
        if (idx < 12672) {
            int p  = idx / 396;
            int s  = idx - p * 396;
            int yy = s / 66;
            int xx = s - yy * 66;
            int gy = y0 + yy - 1;
            int gx = x0 + xx - 1;
            unsigned v = 0;
            if ((unsigned)gy < H_ && (unsigned)gx < W_) {
                size_t base = ((size_t)(2 * p) * H_ + gy) * W_ + gx;
                float f0 = xp[base];
                float f1 = xp[base + HW_];
                v = (unsigned)f2bf(f0) | ((unsigned)f2bf(f1) << 16);
            }
            // dword index: s*32 + swizzled dword-in-row
            xsw[s * 32 + (p ^ ((s & 7) << 2))] = v;
        }
    }
    __syncthreads();

    const int l  = t & 63;
    const int wv = t >> 6;
    const int lr = l & 15;        // fragment "col" lane
    const int lg = l >> 4;        // 0..3
    const int colbase = wv * 16;

    f32x4 acc[4][4];              // [cog][row]
#pragma unroll
    for (int cg = 0; cg < 4; ++cg)
#pragma unroll
        for (int r = 0; r < 4; ++r) acc[cg][r] = (f32x4){0.f, 0.f, 0.f, 0.f};

    const unsigned short* wb = aggb + (size_t)bz * 9 * COUT_ * CIN_;

#pragma unroll
    for (int tap = 0; tap < 9; ++tap) {
        const int kh = tap / 3;
        const int kw = tap - kh * 3;
#pragma unroll
        for (int half = 0; half < 2; ++half) {
            const int cb = half * 32;
            // A fragments: W[co][ci], co = cg*16 + lr, ci = cb + lg*8 + j
            short8 af[4];
#pragma unroll
            for (int cg = 0; cg < 4; ++cg) {
                int co = cg * 16 + lr;
                af[cg] = *(const short8*)&wb[(tap * COUT_ + co) * CIN_ + cb + lg * 8];
            }
            // B fragments: X[ci][pixel], pixel col = colbase+lr, rows r=0..3
            short8 bfv[4];
            const int chunk = half * 4 + lg;          // 16B slot index 0..7
#pragma unroll
            for (int r = 0; r < 4; ++r) {
                int s = (r + kh) * 66 + colbase + lr + kw;
                int e = s * 64 + ((chunk ^ (s & 7)) << 3);
                bfv[r] = *(const short8*)&xs[e];
            }
#pragma unroll
            for (int cg = 0; cg < 4; ++cg)
#pragma unroll
                for (int r = 0; r < 4; ++r)
                    acc[cg][r] = __builtin_amdgcn_mfma_f32_16x16x32_bf16(
                        af[cg], bfv[r], acc[cg][r], 0, 0, 0);
        }
    }

    // ---- epilogue: bias + store. D: col=lr -> pixel, row=4*lg+g -> cout ----
    const size_t obase = (size_t)bz * COUT_ * HW_;
#pragma unroll
    for (int cg = 0; cg < 4; ++cg) {
#pragma unroll
        for (int g = 0; g < 4; ++g) {
            int co = cg * 16 + lg * 4 + g;
            float bs = bias[co];
#pragma unroll
            for (int r = 0; r < 4; ++r) {
                out[obase + (size_t)co * HW_ + (size_t)(y0 + r) * W_ + x0 + colbase + lr]
                    = acc[cg][r][g] + bs;
            }
        }
    }
}

extern "C" void kernel_launch(void* const* d_in, const int* in_sizes, int n_in,
                              void* d_out, int out_size, void* d_ws, size_t ws_size,
                              hipStream_t stream) {
    const float* x      = (const float*)d_in[0];
    const float* att    = (const float*)d_in[1];
    const float* weight = (const float*)d_in[2];
    const float* tb     = (const float*)d_in[3];
    const float* tq     = (const float*)d_in[4];
    const float* tn     = (const float*)d_in[5];
    const float* tx     = (const float*)d_in[6];
    const float* mb     = (const float*)d_in[7];
    const float* mq     = (const float*)d_in[8];
    const float* mn     = (const float*)d_in[9];
    const float* mx     = (const float*)d_in[10];
    const float* bias   = (const float*)d_in[11];

    unsigned short* aggb = (unsigned short*)d_ws;   // 294912 bf16 = 590 KB
    float* outp = (float*)d_out;

    int n_agg = B_ * 9 * COUT_ * CIN_;
    prep_weights_kernel<<<(n_agg + 255) / 256, 256, 0, stream>>>(
        att, weight, tb, tq, tn, tx, mb, mq, mn, mx, aggb);

    dim3 grid(W_ / 64, H_ / 4, B_);   // (4, 64, 8)
    conv_kernel<<<grid, 256, 0, stream>>>(x, aggb, bias, outp);
}